// Round 1
// baseline (2310.744 us; speedup 1.0000x reference)
//
#include <hip/hip_runtime.h>

#define E_ 32
#define T_ 4096
#define K_ 4
#define H_ 2048
#define I_ 1408
#define CAP 1024   // 2*T*K/E, matches reference capacity

typedef __bf16 bf16;
typedef bf16 bf16x4 __attribute__((ext_vector_type(4)));
typedef bf16 bf16x8 __attribute__((ext_vector_type(8)));
typedef float floatx4 __attribute__((ext_vector_type(4)));

// ---------------- routing: assign each (token, k) to a slot in its expert ----
__global__ void route_kernel(const int* __restrict__ idx, const float* __restrict__ w,
                             int* __restrict__ cnt, int* __restrict__ tok,
                             float* __restrict__ wsl) {
    int i = blockIdx.x * blockDim.x + threadIdx.x;
    if (i >= T_ * K_) return;
    int e = idx[i];
    int slot = atomicAdd(&cnt[e], 1);
    if (slot < CAP) {
        tok[e * CAP + slot] = i / K_;
        wsl[e * CAP + slot] = w[i];
    }
}

// ---------------- GEMM1: Xg[n_e,H] x gate_up^T -> SwiGLU -> Abuf bf16 -------
// block: 128 slots x 64 intermediate cols (gate AND up computed together)
__global__ __launch_bounds__(256) void gemm1_kernel(
    const float* __restrict__ x, const float* __restrict__ gu,
    const int* __restrict__ cnt, const int* __restrict__ tok,
    bf16* __restrict__ abuf) {
    const int e = blockIdx.z;
    const int ne = min(cnt[e], CAP);
    const int m0 = blockIdx.y * 128;
    if (m0 >= ne) return;
    const int i0 = blockIdx.x * 64;

    __shared__ __align__(16) bf16 As[128 * 72];
    __shared__ __align__(16) bf16 Bg[64 * 72];
    __shared__ __align__(16) bf16 Bu[64 * 72];

    const int t = threadIdx.x;
    const int c4 = t & 15, r0 = t >> 4;

    // A: 8 rows/thread, gathered via token index (computed once)
    const float* ap[8];
#pragma unroll
    for (int i = 0; i < 8; ++i) {
        int slot = m0 + r0 + 16 * i;
        ap[i] = (slot < ne) ? (x + (size_t)tok[e * CAP + slot] * H_ + 4 * c4) : nullptr;
    }
    // B: 4 gate rows + 4 up rows per thread
    const float* gp[4];
    const float* up[4];
#pragma unroll
    for (int i = 0; i < 4; ++i) {
        int row = i0 + r0 + 16 * i;
        gp[i] = gu + ((size_t)e * (2 * I_) + row) * H_ + 4 * c4;
        up[i] = gu + ((size_t)e * (2 * I_) + I_ + row) * H_ + 4 * c4;
    }

    const int lane = t & 63, wid = t >> 6;
    const int wm = wid & 1, wn = wid >> 1;      // 2x2 waves: 64 rows x 32 cols each
    const int lrow = lane & 15, lk = (lane >> 4) * 8;

    floatx4 accg[4][2], accu[4][2];
#pragma unroll
    for (int a = 0; a < 4; ++a)
#pragma unroll
        for (int b = 0; b < 2; ++b)
#pragma unroll
            for (int q = 0; q < 4; ++q) { accg[a][b][q] = 0.f; accu[a][b][q] = 0.f; }

    for (int k0 = 0; k0 < H_; k0 += 64) {
#pragma unroll
        for (int i = 0; i < 8; ++i) {
            float4 v = ap[i] ? *(const float4*)(ap[i] + k0) : make_float4(0.f, 0.f, 0.f, 0.f);
            bf16x4 bv; bv[0] = (bf16)v.x; bv[1] = (bf16)v.y; bv[2] = (bf16)v.z; bv[3] = (bf16)v.w;
            *(bf16x4*)&As[(r0 + 16 * i) * 72 + 4 * c4] = bv;
        }
#pragma unroll
        for (int i = 0; i < 4; ++i) {
            float4 vg = *(const float4*)(gp[i] + k0);
            float4 vu = *(const float4*)(up[i] + k0);
            bf16x4 bg; bg[0] = (bf16)vg.x; bg[1] = (bf16)vg.y; bg[2] = (bf16)vg.z; bg[3] = (bf16)vg.w;
            bf16x4 bu; bu[0] = (bf16)vu.x; bu[1] = (bf16)vu.y; bu[2] = (bf16)vu.z; bu[3] = (bf16)vu.w;
            *(bf16x4*)&Bg[(r0 + 16 * i) * 72 + 4 * c4] = bg;
            *(bf16x4*)&Bu[(r0 + 16 * i) * 72 + 4 * c4] = bu;
        }
        __syncthreads();
#pragma unroll
        for (int ks = 0; ks < 64; ks += 32) {
            bf16x8 af[4], bgf[2], buf[2];
#pragma unroll
            for (int tm = 0; tm < 4; ++tm)
                af[tm] = *(const bf16x8*)&As[(wm * 64 + tm * 16 + lrow) * 72 + ks + lk];
#pragma unroll
            for (int tn = 0; tn < 2; ++tn) {
                bgf[tn] = *(const bf16x8*)&Bg[(wn * 32 + tn * 16 + lrow) * 72 + ks + lk];
                buf[tn] = *(const bf16x8*)&Bu[(wn * 32 + tn * 16 + lrow) * 72 + ks + lk];
            }
#pragma unroll
            for (int tm = 0; tm < 4; ++tm)
#pragma unroll
                for (int tn = 0; tn < 2; ++tn) {
                    accg[tm][tn] = __builtin_amdgcn_mfma_f32_16x16x32_bf16(af[tm], bgf[tn], accg[tm][tn], 0, 0, 0);
                    accu[tm][tn] = __builtin_amdgcn_mfma_f32_16x16x32_bf16(af[tm], buf[tn], accu[tm][tn], 0, 0, 0);
                }
        }
        __syncthreads();
    }

    // epilogue: silu(gate)*up -> bf16 Abuf
#pragma unroll
    for (int tm = 0; tm < 4; ++tm)
#pragma unroll
        for (int tn = 0; tn < 2; ++tn)
#pragma unroll
            for (int j = 0; j < 4; ++j) {
                int slot = m0 + wm * 64 + tm * 16 + (lane >> 4) * 4 + j;
                if (slot < ne) {
                    int col = i0 + wn * 32 + tn * 16 + (lane & 15);
                    float g = accg[tm][tn][j], u = accu[tm][tn][j];
                    float a = (g / (1.f + __expf(-g))) * u;
                    abuf[(size_t)(e * CAP + slot) * I_ + col] = (bf16)a;
                }
            }
}

// ---------------- GEMM2: A[n_e,I] x down^T -> weighted atomic scatter -------
__global__ __launch_bounds__(256) void gemm2_kernel(
    const bf16* __restrict__ abuf, const float* __restrict__ dn,
    const int* __restrict__ cnt, const int* __restrict__ tok,
    const float* __restrict__ wsl, float* __restrict__ out) {
    const int e = blockIdx.z;
    const int ne = min(cnt[e], CAP);
    const int m0 = blockIdx.y * 128;
    if (m0 >= ne) return;
    const int n0 = blockIdx.x * 128;

    __shared__ __align__(16) bf16 As[128 * 72];
    __shared__ __align__(16) bf16 Bs[128 * 72];

    const int t = threadIdx.x;

    // A staging: bf16 source, 16B chunks. 4 rows/thread.
    const int ca = t & 7, ra = t >> 3;
    const bf16* ap[4];
#pragma unroll
    for (int i = 0; i < 4; ++i) {
        int slot = m0 + ra + 32 * i;
        ap[i] = (slot < ne) ? (abuf + (size_t)(e * CAP + slot) * I_ + 8 * ca) : nullptr;
    }
    // B staging: fp32 down_proj rows (N=H dim), 8 rows/thread
    const int c4 = t & 15, rb = t >> 4;
    const float* bp[8];
#pragma unroll
    for (int i = 0; i < 8; ++i) {
        int row = n0 + rb + 16 * i;
        bp[i] = dn + (size_t)e * H_ * I_ + (size_t)row * I_ + 4 * c4;
    }

    const int lane = t & 63, wid = t >> 6;
    const int wm = wid & 1, wn = wid >> 1;      // 2x2 waves: 64x64 each
    const int lrow = lane & 15, lk = (lane >> 4) * 8;

    floatx4 acc[4][4];
#pragma unroll
    for (int a = 0; a < 4; ++a)
#pragma unroll
        for (int b = 0; b < 4; ++b)
#pragma unroll
            for (int q = 0; q < 4; ++q) acc[a][b][q] = 0.f;

    for (int k0 = 0; k0 < I_; k0 += 64) {
#pragma unroll
        for (int i = 0; i < 4; ++i) {
            bf16x8 v;
            if (ap[i]) v = *(const bf16x8*)(ap[i] + k0);
            else { for (int q = 0; q < 8; ++q) v[q] = (bf16)0.f; }
            *(bf16x8*)&As[(ra + 32 * i) * 72 + 8 * ca] = v;
        }
#pragma unroll
        for (int i = 0; i < 8; ++i) {
            float4 v = *(const float4*)(bp[i] + k0);
            bf16x4 bv; bv[0] = (bf16)v.x; bv[1] = (bf16)v.y; bv[2] = (bf16)v.z; bv[3] = (bf16)v.w;
            *(bf16x4*)&Bs[(rb + 16 * i) * 72 + 4 * c4] = bv;
        }
        __syncthreads();
#pragma unroll
        for (int ks = 0; ks < 64; ks += 32) {
            bf16x8 af[4], bf[4];
#pragma unroll
            for (int tm = 0; tm < 4; ++tm)
                af[tm] = *(const bf16x8*)&As[(wm * 64 + tm * 16 + lrow) * 72 + ks + lk];
#pragma unroll
            for (int tn = 0; tn < 4; ++tn)
                bf[tn] = *(const bf16x8*)&Bs[(wn * 64 + tn * 16 + lrow) * 72 + ks + lk];
#pragma unroll
            for (int tm = 0; tm < 4; ++tm)
#pragma unroll
                for (int tn = 0; tn < 4; ++tn)
                    acc[tm][tn] = __builtin_amdgcn_mfma_f32_16x16x32_bf16(af[tm], bf[tn], acc[tm][tn], 0, 0, 0);
        }
        __syncthreads();
    }

    // epilogue: scale by router weight, scatter-add into out
#pragma unroll
    for (int tm = 0; tm < 4; ++tm)
#pragma unroll
        for (int j = 0; j < 4; ++j) {
            int slot = m0 + wm * 64 + tm * 16 + (lane >> 4) * 4 + j;
            if (slot < ne) {
                int tk = tok[e * CAP + slot];
                float ww = wsl[e * CAP + slot];
#pragma unroll
                for (int tn = 0; tn < 4; ++tn) {
                    int col = n0 + wn * 64 + tn * 16 + (lane & 15);
                    atomicAdd(&out[(size_t)tk * H_ + col], acc[tm][tn][j] * ww);
                }
            }
        }
}

extern "C" void kernel_launch(void* const* d_in, const int* in_sizes, int n_in,
                              void* d_out, int out_size, void* d_ws, size_t ws_size,
                              hipStream_t stream) {
    const float* x   = (const float*)d_in[0];   // [T, H]
    const int*   idx = (const int*)d_in[1];     // [T, K]
    const float* tkw = (const float*)d_in[2];   // [T, K]
    const float* gu  = (const float*)d_in[3];   // [E, 2I, H]
    const float* dn  = (const float*)d_in[4];   // [E, H, I]
    float* out = (float*)d_out;                 // [T, H]

    // workspace layout
    int*   cnt  = (int*)d_ws;                   // 64 ints (32 used)
    int*   tok  = cnt + 64;                     // E*CAP
    float* wsl  = (float*)(tok + E_ * CAP);     // E*CAP
    bf16*  abuf = (bf16*)(wsl + E_ * CAP);      // E*CAP*I bf16 (~92 MB)

    hipMemsetAsync(cnt, 0, 64 * sizeof(int), stream);
    hipMemsetAsync(out, 0, (size_t)T_ * H_ * sizeof(float), stream);

    route_kernel<<<(T_ * K_ + 255) / 256, 256, 0, stream>>>(idx, tkw, cnt, tok, wsl);
    gemm1_kernel<<<dim3(I_ / 64, CAP / 128, E_), 256, 0, stream>>>(x, gu, cnt, tok, abuf);
    gemm2_kernel<<<dim3(H_ / 128, CAP / 128, E_), 256, 0, stream>>>(abuf, dn, cnt, tok, wsl, out);
}